// Round 1
// baseline (1060.524 us; speedup 1.0000x reference)
//
#include <hip/hip_runtime.h>

#define HDIM 64
#define NEG_SLOPE 0.01f

static __device__ __forceinline__ float lane_bcast(float v, int k) {
    return __int_as_float(__builtin_amdgcn_readlane(__float_as_int(v), k));
}

__global__ void k_zero(int N, int* deg, float* signsum) {
    int i = blockIdx.x * blockDim.x + threadIdx.x;
    if (i < N) { deg[i] = 0; signsum[i] = 0.f; }
}

__global__ void k_deg(int E, const int* __restrict__ src, const int* __restrict__ dst,
                      int* deg, float* signsum) {
    int e = blockIdx.x * blockDim.x + threadIdx.x;
    if (e >= E) return;
    int s = src[e], d = dst[e];
    atomicAdd(&deg[d], 1);
    float sg = (s > d) ? 1.f : ((s < d) ? -1.f : 0.f);
    if (sg != 0.f) atomicAdd(&signsum[d], sg);
}

__global__ void k_bsum(int N, const int* __restrict__ deg, int* bsum) {
    __shared__ int sdata[256];
    int i = blockIdx.x * 256 + threadIdx.x;
    sdata[threadIdx.x] = (i < N) ? deg[i] : 0;
    __syncthreads();
    for (int s = 128; s > 0; s >>= 1) {
        if (threadIdx.x < s) sdata[threadIdx.x] += sdata[threadIdx.x + s];
        __syncthreads();
    }
    if (threadIdx.x == 0) bsum[blockIdx.x] = sdata[0];
}

__global__ void k_scan(int N, const int* __restrict__ deg, const int* __restrict__ bsum,
                       int* rowptr, int* cursor) {
    __shared__ int sdata[256];
    int b = blockIdx.x;
    int i = b * 256 + threadIdx.x;
    int v = (i < N) ? deg[i] : 0;
    int off = 0;
    for (int j = 0; j < b; ++j) off += bsum[j];
    sdata[threadIdx.x] = v;
    __syncthreads();
    int x = v;
    for (int s = 1; s < 256; s <<= 1) {
        int tprev = (threadIdx.x >= (unsigned)s) ? sdata[threadIdx.x - s] : 0;
        __syncthreads();
        x += tprev;
        sdata[threadIdx.x] = x;
        __syncthreads();
    }
    int exc = x - v;
    if (i < N) { rowptr[i] = off + exc; cursor[i] = off + exc; }
    if (i == N - 1) rowptr[N] = off + x;
}

__global__ void k_fill(int E, const int* __restrict__ src, const int* __restrict__ dst,
                       int* cursor, int* csr_src) {
    int e = blockIdx.x * blockDim.x + threadIdx.x;
    if (e >= E) return;
    int d = dst[e];
    int p = atomicAdd(&cursor[d], 1);
    csr_src[p] = src[e];
}

// Amid[l][k][h] = W_mid[l][k][h] - W_mid[l][64+k][h]
__global__ void k_prep(int total, const float* __restrict__ W_mid, float* __restrict__ Amid) {
    int i = blockIdx.x * blockDim.x + threadIdx.x;
    if (i >= total) return;
    int l = i >> 12;              // / 4096
    int r = (i >> 6) & 63;
    int h = i & 63;
    const float* W = W_mid + (size_t)l * 129 * 64;
    Amid[i] = W[r * 64 + h] - W[(64 + r) * 64 + h];
}

// conv_in: x [N,1] -> xout [N,64]
__global__ void k_in(int N, const float* __restrict__ x0,
                     const int* __restrict__ rowptr, const int* __restrict__ csr_src,
                     const float* __restrict__ signsum,
                     const float* __restrict__ W_in, const float* __restrict__ b_in,
                     float* __restrict__ xout) {
    int wid = blockIdx.x * (blockDim.x >> 6) + (threadIdx.x >> 6);
    int lane = threadIdx.x & 63;
    if (wid >= N) return;
    int beg = rowptr[wid], end = rowptr[wid + 1];
    int deg = end - beg;
    float s = 0.f;
    for (int e = beg + lane; e < end; e += 64) s += x0[csr_src[e]];
    for (int m = 32; m >= 1; m >>= 1) s += __shfl_xor(s, m, 64);
    float invd = 1.f / (float)max(deg, 1);
    float mean = s * invd;
    float xi = x0[wid];
    float w1 = W_in[lane], w2 = W_in[64 + lane], w3 = W_in[128 + lane];
    float y = xi * (w1 - w2) + mean * w2 + signsum[wid] * invd * w3 + b_in[lane];
    if (deg == 0) y = 0.f;
    xout[wid * HDIM + lane] = y;
}

// fused mid conv: aggregate mean(x_j), matvec [xi;M]@[A;W2], bias+sign, (+res), leaky
template <bool RES>
__global__ void k_mid(int N, const float* __restrict__ xin,
                      const float* __restrict__ xres, float* __restrict__ xout,
                      const int* __restrict__ rowptr, const int* __restrict__ csr_src,
                      const float* __restrict__ signsum,
                      const float* __restrict__ A, const float* __restrict__ W2,
                      const float* __restrict__ W3, const float* __restrict__ bias) {
    int wid = blockIdx.x * (blockDim.x >> 6) + (threadIdx.x >> 6);
    int lane = threadIdx.x & 63;
    if (wid >= N) return;
    int beg = __builtin_amdgcn_readfirstlane(rowptr[wid]);
    int end = __builtin_amdgcn_readfirstlane(rowptr[wid + 1]);
    int deg = end - beg;
    float acc = 0.f;
    for (int tbase = beg; tbase < end; tbase += 64) {
        int cnt = min(64, end - tbase);
        int sv = (lane < cnt) ? csr_src[tbase + lane] : 0;
        for (int u = 0; u < cnt; ++u) {
            int sidx = __builtin_amdgcn_readlane(sv, u);
            acc += xin[sidx * HDIM + lane];
        }
    }
    float invd = 1.f / (float)max(deg, 1);
    float M = acc * invd;
    float xi = xin[wid * HDIM + lane];
    float y = signsum[wid] * invd * W3[lane] + bias[lane];
#pragma unroll 8
    for (int k = 0; k < 64; ++k) {
        float xk = lane_bcast(xi, k);
        float Mk = lane_bcast(M, k);
        y += xk * A[k * HDIM + lane] + Mk * W2[k * HDIM + lane];
    }
    if (deg == 0) y = 0.f;
    if (RES) y += xres[wid * HDIM + lane];
    y = (y > 0.f) ? y : NEG_SLOPE * y;
    xout[wid * HDIM + lane] = y;
}

// t[i] = dot(xA[i], W_out[64:128])
__global__ void k_t(int N, const float* __restrict__ xA, const float* __restrict__ W_out,
                    float* __restrict__ t) {
    int wid = blockIdx.x * (blockDim.x >> 6) + (threadIdx.x >> 6);
    int lane = threadIdx.x & 63;
    if (wid >= N) return;
    float p = xA[wid * HDIM + lane] * W_out[64 + lane];
    for (int m = 32; m >= 1; m >>= 1) p += __shfl_xor(p, m, 64);
    if (lane == 0) t[wid] = p;
}

// conv_out + residual x
__global__ void k_out(int N, const float* __restrict__ xA, const float* __restrict__ x0,
                      const int* __restrict__ rowptr, const int* __restrict__ csr_src,
                      const float* __restrict__ signsum, const float* __restrict__ t,
                      const float* __restrict__ W_out, const float* __restrict__ b_out,
                      float* __restrict__ out) {
    int wid = blockIdx.x * (blockDim.x >> 6) + (threadIdx.x >> 6);
    int lane = threadIdx.x & 63;
    if (wid >= N) return;
    int beg = rowptr[wid], end = rowptr[wid + 1];
    int deg = end - beg;
    float s = 0.f;
    for (int e = beg + lane; e < end; e += 64) s += t[csr_src[e]];
    float p = xA[wid * HDIM + lane] * (W_out[lane] - W_out[64 + lane]);
    for (int m = 32; m >= 1; m >>= 1) {
        s += __shfl_xor(s, m, 64);
        p += __shfl_xor(p, m, 64);
    }
    float invd = 1.f / (float)max(deg, 1);
    float y = p + s * invd + signsum[wid] * invd * W_out[128] + b_out[0];
    if (deg == 0) y = 0.f;
    if (lane == 0) out[wid] = y + x0[wid];
}

extern "C" void kernel_launch(void* const* d_in, const int* in_sizes, int n_in,
                              void* d_out, int out_size, void* d_ws, size_t ws_size,
                              hipStream_t stream) {
    const float* x0    = (const float*)d_in[0];
    const int*   ei    = (const int*)d_in[1];
    const float* W_in  = (const float*)d_in[2];
    const float* b_in  = (const float*)d_in[3];
    const float* W_mid = (const float*)d_in[4];
    const float* b_mid = (const float*)d_in[5];
    const float* W_out = (const float*)d_in[6];
    const float* b_out = (const float*)d_in[7];
    float* out = (float*)d_out;

    const int N = in_sizes[0];            // 50000
    const int E = in_sizes[1] / 2;        // 1600000
    const int L = in_sizes[4] / (129 * 64); // 6 mid layers
    const int* src = ei;
    const int* dst = ei + E;

    char* p = (char*)d_ws;
    int* deg      = (int*)p;  p += (size_t)N * 4;
    int* rowptr   = (int*)p;  p += (size_t)(N + 1) * 4;
    int* cursor   = (int*)p;  p += (size_t)N * 4;
    int* bsum     = (int*)p;  p += 4096;               // up to 1024 scan blocks
    int* csr_src  = (int*)p;  p += (size_t)E * 4;
    float* signsum= (float*)p; p += (size_t)N * 4;
    float* Amid   = (float*)p; p += (size_t)L * HDIM * HDIM * 4;
    float* t      = (float*)p; p += (size_t)N * 4;
    float* xA     = (float*)p; p += (size_t)N * HDIM * 4;
    float* xB     = (float*)p; p += (size_t)N * HDIM * 4;

    const int nb_n = (N + 255) / 256;
    const int nb_e = (E + 255) / 256;
    const int nb_w = (N + 3) / 4;          // 4 waves (nodes) per 256-thread block
    const int atotal = L * HDIM * HDIM;

    k_zero<<<nb_n, 256, 0, stream>>>(N, deg, signsum);
    k_deg<<<nb_e, 256, 0, stream>>>(E, src, dst, deg, signsum);
    k_bsum<<<nb_n, 256, 0, stream>>>(N, deg, bsum);
    k_scan<<<nb_n, 256, 0, stream>>>(N, deg, bsum, rowptr, cursor);
    k_fill<<<nb_e, 256, 0, stream>>>(E, src, dst, cursor, csr_src);
    k_prep<<<(atotal + 255) / 256, 256, 0, stream>>>(atotal, W_mid, Amid);

    k_in<<<nb_w, 256, 0, stream>>>(N, x0, rowptr, csr_src, signsum, W_in, b_in, xA);

    for (int l = 0; l < L / 2; ++l) {
        const float* Wa = W_mid + (size_t)(2 * l) * 129 * 64;
        const float* Wb = W_mid + (size_t)(2 * l + 1) * 129 * 64;
        // x1 = leaky(conv(x2))          : xA -> xB
        k_mid<false><<<nb_w, 256, 0, stream>>>(
            N, xA, nullptr, xB, rowptr, csr_src, signsum,
            Amid + (size_t)(2 * l) * HDIM * HDIM, Wa + 64 * 64, Wa + 128 * 64,
            b_mid + (size_t)(2 * l) * HDIM);
        // x2 = leaky(conv(x1) + x2)     : xB (+xA) -> xA
        k_mid<true><<<nb_w, 256, 0, stream>>>(
            N, xB, xA, xA, rowptr, csr_src, signsum,
            Amid + (size_t)(2 * l + 1) * HDIM * HDIM, Wb + 64 * 64, Wb + 128 * 64,
            b_mid + (size_t)(2 * l + 1) * HDIM);
    }

    k_t<<<nb_w, 256, 0, stream>>>(N, xA, W_out, t);
    k_out<<<nb_w, 256, 0, stream>>>(N, xA, x0, rowptr, csr_src, signsum, t,
                                    W_out, b_out, out);
}

// Round 2
// 913.073 us; speedup vs baseline: 1.1615x; 1.1615x over previous
//
#include <hip/hip_runtime.h>

#define HDIM 64
#define NEG_SLOPE 0.01f

static __device__ __forceinline__ float lane_bcast(float v, int k) {
    return __int_as_float(__builtin_amdgcn_readlane(__float_as_int(v), k));
}
static __device__ __forceinline__ unsigned short f2bf(float f) {
    unsigned u = __float_as_uint(f);
    unsigned r = (u + 0x7FFFu + ((u >> 16) & 1u)) >> 16;
    return (unsigned short)r;
}
static __device__ __forceinline__ float bf_lo(unsigned d) { return __uint_as_float(d << 16); }
static __device__ __forceinline__ float bf_hi(unsigned d) { return __uint_as_float(d & 0xffff0000u); }

__global__ void k_zero(int N, unsigned* pk) {
    int i = blockIdx.x * blockDim.x + threadIdx.x;
    if (i < N) pk[i] = 0u;
}

// one packed atomic per edge: deg in bits [20:31], lt=#(s<d) in [10:19], eq in [0:9]
__global__ void k_deg(int E, const int* __restrict__ src, const int* __restrict__ dst,
                      unsigned* pk) {
    int e = blockIdx.x * blockDim.x + threadIdx.x;
    if (e >= E) return;
    int s = src[e], d = dst[e];
    unsigned val = (1u << 20) | ((s < d) ? (1u << 10) : 0u) | ((s == d) ? 1u : 0u);
    atomicAdd(&pk[d], val);
}

__global__ void k_bsum(int N, const unsigned* __restrict__ pk, int* bsum) {
    __shared__ int sdata[256];
    int i = blockIdx.x * 256 + threadIdx.x;
    sdata[threadIdx.x] = (i < N) ? (int)(pk[i] >> 20) : 0;
    __syncthreads();
    for (int s = 128; s > 0; s >>= 1) {
        if (threadIdx.x < s) sdata[threadIdx.x] += sdata[threadIdx.x + s];
        __syncthreads();
    }
    if (threadIdx.x == 0) bsum[blockIdx.x] = sdata[0];
}

__global__ void k_scan(int N, const unsigned* __restrict__ pk, const int* __restrict__ bsum,
                       int* rowptr, int* cursor, float* ssinv) {
    __shared__ int sdata[256];
    int b = blockIdx.x;
    int i = b * 256 + threadIdx.x;
    unsigned p = (i < N) ? pk[i] : 0u;
    int deg = (int)(p >> 20);
    int off = 0;
    for (int j = 0; j < b; ++j) off += bsum[j];
    sdata[threadIdx.x] = deg;
    __syncthreads();
    int x = deg;
    for (int s = 1; s < 256; s <<= 1) {
        int tprev = (threadIdx.x >= (unsigned)s) ? sdata[threadIdx.x - s] : 0;
        __syncthreads();
        x += tprev;
        sdata[threadIdx.x] = x;
        __syncthreads();
    }
    int exc = x - deg;
    if (i < N) {
        rowptr[i] = off + exc;
        cursor[i] = off + exc;
        int lt = (int)((p >> 10) & 1023u);
        int eq = (int)(p & 1023u);
        float ss = (float)(deg - eq - 2 * lt);
        ssinv[i] = ss / (float)max(deg, 1);
    }
    if (i == N - 1) rowptr[N] = off + x;
}

__global__ void k_fill(int E, const int* __restrict__ src, const int* __restrict__ dst,
                       int* cursor, int* csr_src) {
    int e = blockIdx.x * blockDim.x + threadIdx.x;
    if (e >= E) return;
    int d = dst[e];
    int p = atomicAdd(&cursor[d], 1);
    csr_src[p] = src[e];
}

// AW[l][k][h] = {A=W[k][h]-W[64+k][h], W2=W[64+k][h]} interleaved for float2 loads
__global__ void k_prep(int total, const float* __restrict__ W_mid, float* __restrict__ AW) {
    int i = blockIdx.x * blockDim.x + threadIdx.x;
    if (i >= total) return;
    int l = i >> 12;
    int k = (i >> 6) & 63;
    int h = i & 63;
    const float* W = W_mid + (size_t)l * 129 * 64;
    float w1 = W[k * 64 + h];
    float w2 = W[(64 + k) * 64 + h];
    size_t o = ((size_t)l * 4096 + k * 64 + h) * 2;
    AW[o] = w1 - w2;
    AW[o + 1] = w2;
}

// conv_in: x [N,1] fp32 -> xout packed bf16 [N,32] dwords
__global__ void k_in(int N, const float* __restrict__ x0,
                     const int* __restrict__ rowptr, const int* __restrict__ csr_src,
                     const float* __restrict__ ssinv,
                     const float* __restrict__ W_in, const float* __restrict__ b_in,
                     unsigned* __restrict__ xoutP) {
    int wid = blockIdx.x * (blockDim.x >> 6) + (threadIdx.x >> 6);
    int lane = threadIdx.x & 63;
    if (wid >= N) return;
    int beg = rowptr[wid], end = rowptr[wid + 1];
    int deg = end - beg;
    float s = 0.f;
    for (int e = beg + lane; e < end; e += 64) s += x0[csr_src[e]];
    for (int m = 32; m >= 1; m >>= 1) s += __shfl_xor(s, m, 64);
    float invd = 1.f / (float)max(deg, 1);
    float mean = s * invd;
    float xi = x0[wid];
    float w1 = W_in[lane], w2 = W_in[64 + lane], w3 = W_in[128 + lane];
    float y = xi * (w1 - w2) + mean * w2 + ssinv[wid] * w3 + b_in[lane];
    if (deg == 0) y = 0.f;
    float ylo = __shfl(y, (2 * lane) & 63, 64);
    float yhi = __shfl(y, (2 * lane + 1) & 63, 64);
    unsigned pkd = ((unsigned)f2bf(yhi) << 16) | (unsigned)f2bf(ylo);
    if (lane < 32) xoutP[(size_t)wid * 32 + lane] = pkd;
}

// fused mid conv on packed-bf16 features
template <bool RES, bool TOUT>
__global__ void k_mid(int N, const unsigned* __restrict__ xinP,
                      const unsigned* __restrict__ xresP, unsigned* __restrict__ xoutP,
                      const int* __restrict__ rowptr, const int* __restrict__ csr_src,
                      const float* __restrict__ ssinv,
                      const float* __restrict__ AW,
                      const float* __restrict__ W3, const float* __restrict__ bias,
                      const float* __restrict__ Wt, float* __restrict__ t) {
    int wid = blockIdx.x * (blockDim.x >> 6) + (threadIdx.x >> 6);
    int lane = threadIdx.x & 63;
    if (wid >= N) return;
    int beg = __builtin_amdgcn_readfirstlane(rowptr[wid]);
    int end = __builtin_amdgcn_readfirstlane(rowptr[wid + 1]);
    int deg = end - beg;
    int w = lane & 31;
    int half = lane >> 5;
    float acc0 = 0.f, acc1 = 0.f;
    for (int tbase = beg; tbase < end; tbase += 64) {
        int cnt = min(64, end - tbase);
        int sv = (lane < cnt) ? csr_src[tbase + lane] : -1;
        for (int u = 0; u < cnt; u += 4) {
            int sa = __builtin_amdgcn_readlane(sv, u);
            int sb = __builtin_amdgcn_readlane(sv, u + 1);
            int sc = __builtin_amdgcn_readlane(sv, u + 2);
            int sd = __builtin_amdgcn_readlane(sv, u + 3);
            int s1 = half ? sb : sa;
            int s2 = half ? sd : sc;
            if (s1 >= 0) {
                unsigned d1 = xinP[(size_t)s1 * 32 + w];
                acc0 += bf_lo(d1);
                acc1 += bf_hi(d1);
            }
            if (s2 >= 0) {
                unsigned d2 = xinP[(size_t)s2 * 32 + w];
                acc0 += bf_lo(d2);
                acc1 += bf_hi(d2);
            }
        }
    }
    acc0 += __shfl_xor(acc0, 32, 64);
    acc1 += __shfl_xor(acc1, 32, 64);
    float invd = 1.f / (float)max(deg, 1);
    float M0 = acc0 * invd;   // mean feature 2w
    float M1 = acc1 * invd;   // mean feature 2w+1
    unsigned xw = xinP[(size_t)wid * 32 + (lane >> 1)];
    float xi = (lane & 1) ? bf_hi(xw) : bf_lo(xw);
    float y = ssinv[wid] * W3[lane] + bias[lane];
#pragma unroll
    for (int k = 0; k < 64; ++k) {
        float xk = lane_bcast(xi, k);
        float Mk = lane_bcast((k & 1) ? M1 : M0, k >> 1);
        const float2 wv = *(const float2*)&AW[(size_t)(k * 64 + lane) * 2];
        y += xk * wv.x + Mk * wv.y;
    }
    if (deg == 0) y = 0.f;
    if (RES) {
        unsigned rw = xresP[(size_t)wid * 32 + (lane >> 1)];
        y += (lane & 1) ? bf_hi(rw) : bf_lo(rw);
    }
    y = (y > 0.f) ? y : NEG_SLOPE * y;
    if (TOUT) {
        float tp = y * Wt[lane];
        for (int m = 32; m >= 1; m >>= 1) tp += __shfl_xor(tp, m, 64);
        if (lane == 0) t[wid] = tp;
    }
    float ylo = __shfl(y, (2 * lane) & 63, 64);
    float yhi = __shfl(y, (2 * lane + 1) & 63, 64);
    unsigned pkd = ((unsigned)f2bf(yhi) << 16) | (unsigned)f2bf(ylo);
    if (lane < 32) xoutP[(size_t)wid * 32 + lane] = pkd;
}

// conv_out + residual x
__global__ void k_out(int N, const unsigned* __restrict__ xAP, const float* __restrict__ x0,
                      const int* __restrict__ rowptr, const int* __restrict__ csr_src,
                      const float* __restrict__ ssinv, const float* __restrict__ t,
                      const float* __restrict__ W_out, const float* __restrict__ b_out,
                      float* __restrict__ out) {
    int wid = blockIdx.x * (blockDim.x >> 6) + (threadIdx.x >> 6);
    int lane = threadIdx.x & 63;
    if (wid >= N) return;
    int beg = rowptr[wid], end = rowptr[wid + 1];
    int deg = end - beg;
    float s = 0.f;
    for (int e = beg + lane; e < end; e += 64) s += t[csr_src[e]];
    unsigned xw = xAP[(size_t)wid * 32 + (lane >> 1)];
    float xf = (lane & 1) ? bf_hi(xw) : bf_lo(xw);
    float p = xf * (W_out[lane] - W_out[64 + lane]);
    for (int m = 32; m >= 1; m >>= 1) {
        s += __shfl_xor(s, m, 64);
        p += __shfl_xor(p, m, 64);
    }
    float invd = 1.f / (float)max(deg, 1);
    float y = p + s * invd + ssinv[wid] * W_out[128] + b_out[0];
    if (deg == 0) y = 0.f;
    if (lane == 0) out[wid] = y + x0[wid];
}

extern "C" void kernel_launch(void* const* d_in, const int* in_sizes, int n_in,
                              void* d_out, int out_size, void* d_ws, size_t ws_size,
                              hipStream_t stream) {
    const float* x0    = (const float*)d_in[0];
    const int*   ei    = (const int*)d_in[1];
    const float* W_in  = (const float*)d_in[2];
    const float* b_in  = (const float*)d_in[3];
    const float* W_mid = (const float*)d_in[4];
    const float* b_mid = (const float*)d_in[5];
    const float* W_out = (const float*)d_in[6];
    const float* b_out = (const float*)d_in[7];
    float* out = (float*)d_out;

    const int N = in_sizes[0];
    const int E = in_sizes[1] / 2;
    const int L = in_sizes[4] / (129 * 64);   // 6 mid layers
    const int* src = ei;
    const int* dst = ei + E;

    // 16B-aligned blocks first
    char* p = (char*)d_ws;
    float* AW     = (float*)p; p += (size_t)L * HDIM * HDIM * 2 * 4;
    unsigned* xAP = (unsigned*)p; p += (size_t)N * 32 * 4;
    unsigned* xBP = (unsigned*)p; p += (size_t)N * 32 * 4;
    int* csr_src  = (int*)p;  p += (size_t)E * 4;
    unsigned* pk  = (unsigned*)p; p += (size_t)N * 4;
    int* rowptr   = (int*)p;  p += (size_t)(N + 1) * 4;
    int* cursor   = (int*)p;  p += (size_t)N * 4;
    int* bsum     = (int*)p;  p += 4096;
    float* ssinv  = (float*)p; p += (size_t)N * 4;
    float* t      = (float*)p; p += (size_t)N * 4;

    const int nb_n = (N + 255) / 256;
    const int nb_e = (E + 255) / 256;
    const int nb_w = (N + 3) / 4;
    const int atotal = L * HDIM * HDIM;

    k_zero<<<nb_n, 256, 0, stream>>>(N, pk);
    k_deg<<<nb_e, 256, 0, stream>>>(E, src, dst, pk);
    k_bsum<<<nb_n, 256, 0, stream>>>(N, pk, bsum);
    k_scan<<<nb_n, 256, 0, stream>>>(N, pk, bsum, rowptr, cursor, ssinv);
    k_fill<<<nb_e, 256, 0, stream>>>(E, src, dst, cursor, csr_src);
    k_prep<<<(atotal + 255) / 256, 256, 0, stream>>>(atotal, W_mid, AW);

    k_in<<<nb_w, 256, 0, stream>>>(N, x0, rowptr, csr_src, ssinv, W_in, b_in, xAP);

    for (int l = 0; l < L / 2; ++l) {
        const float* Wa = W_mid + (size_t)(2 * l) * 129 * 64;
        const float* Wb = W_mid + (size_t)(2 * l + 1) * 129 * 64;
        bool last = (l == L / 2 - 1);
        // x1 = leaky(conv(x2))       : xAP -> xBP
        k_mid<false, false><<<nb_w, 256, 0, stream>>>(
            N, xAP, nullptr, xBP, rowptr, csr_src, ssinv,
            AW + (size_t)(2 * l) * HDIM * HDIM * 2, Wa + 128 * 64,
            b_mid + (size_t)(2 * l) * HDIM, nullptr, nullptr);
        // x2 = leaky(conv(x1) + x2)  : xBP (+xAP) -> xAP   [+ t on last]
        if (!last) {
            k_mid<true, false><<<nb_w, 256, 0, stream>>>(
                N, xBP, xAP, xAP, rowptr, csr_src, ssinv,
                AW + (size_t)(2 * l + 1) * HDIM * HDIM * 2, Wb + 128 * 64,
                b_mid + (size_t)(2 * l + 1) * HDIM, nullptr, nullptr);
        } else {
            k_mid<true, true><<<nb_w, 256, 0, stream>>>(
                N, xBP, xAP, xAP, rowptr, csr_src, ssinv,
                AW + (size_t)(2 * l + 1) * HDIM * HDIM * 2, Wb + 128 * 64,
                b_mid + (size_t)(2 * l + 1) * HDIM, W_out + 64, t);
        }
    }

    k_out<<<nb_w, 256, 0, stream>>>(N, xAP, x0, rowptr, csr_src, ssinv, t,
                                    W_out, b_out, out);
}

// Round 3
// 541.385 us; speedup vs baseline: 1.9589x; 1.6865x over previous
//
#include <hip/hip_runtime.h>

#define HDIM 64
#define NEG_SLOPE 0.01f
#define CAPB 8192      // bucketed[] region per 128-node bucket
#define BCAP 6144      // LDS staging capacity in k_csr

static __device__ __forceinline__ float lane_bcast(float v, int k) {
    return __int_as_float(__builtin_amdgcn_readlane(__float_as_int(v), k));
}
static __device__ __forceinline__ unsigned short f2bf(float f) {
    unsigned u = __float_as_uint(f);
    unsigned r = (u + 0x7FFFu + ((u >> 16) & 1u)) >> 16;
    return (unsigned short)r;
}
static __device__ __forceinline__ float bf_lo(unsigned d) { return __uint_as_float(d << 16); }
static __device__ __forceinline__ float bf_hi(unsigned d) { return __uint_as_float(d & 0xffff0000u); }

__global__ void k_initcur(int NB, int* gcur) {
    int i = blockIdx.x * blockDim.x + threadIdx.x;
    if (i < NB) gcur[i] = i * CAPB;
}

// Phase 1: bucket edges by dst>>7 into fixed regions; packed u32 = (dst<<16)|src.
__global__ void k_bucket(int E, const int* __restrict__ src, const int* __restrict__ dst,
                         int* gcur, unsigned* __restrict__ bucketed, int NB) {
    __shared__ int lh[512];
    __shared__ int lbase[512];
    int t = threadIdx.x;
    int e0 = blockIdx.x * 8192;
    for (int i = t; i < NB; i += 256) lh[i] = 0;
    __syncthreads();
    for (int k = 0; k < 32; ++k) {
        int e = e0 + k * 256 + t;
        if (e < E) atomicAdd(&lh[((unsigned)dst[e]) >> 7], 1);
    }
    __syncthreads();
    for (int i = t; i < NB; i += 256) {
        int c = lh[i];
        lbase[i] = (c > 0) ? atomicAdd(&gcur[i], c) : 0;
        lh[i] = 0;
    }
    __syncthreads();
    for (int k = 0; k < 32; ++k) {
        int e = e0 + k * 256 + t;
        if (e < E) {
            int d = dst[e], s = src[e];
            int b = ((unsigned)d) >> 7;
            int r = atomicAdd(&lh[b], 1);
            int pos = lbase[b] + r;
            if (pos < (b + 1) * CAPB)
                bucketed[pos] = ((unsigned)d << 16) | (unsigned)s;
        }
    }
}

// Exclusive scan of bucket counts -> gstart; rowptr[N].
__global__ void k_bktscan(int NB, int N, const int* __restrict__ gcur,
                          int* gstart, int* rowptr) {
    __shared__ int sd[512];
    int t = threadIdx.x;
    int c = (t < NB) ? min(gcur[t] - t * CAPB, CAPB) : 0;
    sd[t] = c;
    __syncthreads();
    int x = c;
    for (int s = 1; s < 512; s <<= 1) {
        int p = (t >= s) ? sd[t - s] : 0;
        __syncthreads();
        x += p;
        sd[t] = x;
        __syncthreads();
    }
    if (t < NB) gstart[t] = x - c;
    if (t == NB - 1) {
        gstart[NB] = x;
        rowptr[N] = x;
    }
}

// Phase 2: per bucket, LDS hist+scan over 128 local dsts -> rowptr/ssinv + coalesced csr.
__global__ void k_csr(int N, const unsigned* __restrict__ bucketed, const int* __restrict__ gcur,
                      const int* __restrict__ gstart, unsigned short* __restrict__ csr,
                      int* __restrict__ rowptr, float* __restrict__ ssinv) {
    __shared__ unsigned st[BCAP];
    __shared__ int hist[128], cur[128], sgp[128];
    int b = blockIdx.x, t = threadIdx.x;
    int n0 = b << 7;
    int nn = min(128, N - n0);
    int cnt = min(gcur[b] - b * CAPB, CAPB);
    int base = gstart[b];
    if (t < 128) { hist[t] = 0; sgp[t] = 0; }
    __syncthreads();
    bool single = (cnt <= BCAP);
    for (int off = 0; off < cnt; off += BCAP) {
        int bs = min(BCAP, cnt - off);
        for (int i = t; i < bs; i += 256) {
            unsigned w = bucketed[b * CAPB + off + i];
            if (single) st[i] = w;
            int d = (int)(w >> 16);
            int s = (int)(w & 0xffffu);
            int dl = d - n0;
            atomicAdd(&hist[dl], 1);
            atomicAdd(&sgp[dl], ((s < d) ? 1024 : 0) + ((s == d) ? 1 : 0));
        }
    }
    __syncthreads();
    int deg_t = (t < 128) ? hist[t] : 0;
    int x = deg_t;
    for (int s = 1; s < 128; s <<= 1) {
        int p = (t < 128 && t >= s) ? hist[t - s] : 0;
        __syncthreads();
        if (t < 128) { x += p; hist[t] = x; }
        __syncthreads();
    }
    if (t < 128) {
        int excl = hist[t] - deg_t;
        cur[t] = excl;
        if (t < nn) {
            rowptr[n0 + t] = base + excl;
            int sg = sgp[t];
            int lt = sg >> 10, eq = sg & 1023;
            float ss = (float)(deg_t - eq - 2 * lt);
            ssinv[n0 + t] = (deg_t > 0) ? ss / (float)deg_t : 0.f;
        }
    }
    __syncthreads();
    for (int off = 0; off < cnt; off += BCAP) {
        int bs = min(BCAP, cnt - off);
        if (!single) {
            for (int i = t; i < bs; i += 256) st[i] = bucketed[b * CAPB + off + i];
            __syncthreads();
        }
        for (int i = t; i < bs; i += 256) {
            unsigned w = st[i];
            int dl = (int)(w >> 16) - n0;
            int p = atomicAdd(&cur[dl], 1);
            csr[base + p] = (unsigned short)(w & 0xffffu);
        }
        if (!single) __syncthreads();
    }
}

// AW[l][k][h] = {A=W[k][h]-W[64+k][h], W2=W[64+k][h]} interleaved
__global__ void k_prep(int total, const float* __restrict__ W_mid, float* __restrict__ AW) {
    int i = blockIdx.x * blockDim.x + threadIdx.x;
    if (i >= total) return;
    int l = i >> 12;
    int k = (i >> 6) & 63;
    int h = i & 63;
    const float* W = W_mid + (size_t)l * 129 * 64;
    float w1 = W[k * 64 + h];
    float w2 = W[(64 + k) * 64 + h];
    size_t o = ((size_t)l * 4096 + k * 64 + h) * 2;
    AW[o] = w1 - w2;
    AW[o + 1] = w2;
}

// conv_in: x [N,1] fp32 -> packed bf16 [N,32] dwords
__global__ void k_in(int N, const float* __restrict__ x0,
                     const int* __restrict__ rowptr, const unsigned short* __restrict__ csr,
                     const float* __restrict__ ssinv,
                     const float* __restrict__ W_in, const float* __restrict__ b_in,
                     unsigned* __restrict__ xoutP) {
    int wid = blockIdx.x * (blockDim.x >> 6) + (threadIdx.x >> 6);
    int lane = threadIdx.x & 63;
    if (wid >= N) return;
    int beg = rowptr[wid], end = rowptr[wid + 1];
    int deg = end - beg;
    float s = 0.f;
    for (int e = beg + lane; e < end; e += 64) s += x0[csr[e]];
    for (int m = 32; m >= 1; m >>= 1) s += __shfl_xor(s, m, 64);
    float invd = 1.f / (float)max(deg, 1);
    float mean = s * invd;
    float xi = x0[wid];
    float w1 = W_in[lane], w2 = W_in[64 + lane], w3 = W_in[128 + lane];
    float y = xi * (w1 - w2) + mean * w2 + ssinv[wid] * w3 + b_in[lane];
    if (deg == 0) y = 0.f;
    float ylo = __shfl(y, (2 * lane) & 63, 64);
    float yhi = __shfl(y, (2 * lane + 1) & 63, 64);
    unsigned pkd = ((unsigned)f2bf(yhi) << 16) | (unsigned)f2bf(ylo);
    if (lane < 32) xoutP[(size_t)wid * 32 + lane] = pkd;
}

// fused mid conv on packed-bf16 features; AW staged in LDS; 8 nodes / 512-thread block
template <bool RES, bool TOUT>
__global__ __launch_bounds__(512) void k_mid(
        int N, const unsigned* __restrict__ xinP,
        const unsigned* __restrict__ xresP, unsigned* __restrict__ xoutP,
        const int* __restrict__ rowptr, const unsigned short* __restrict__ csr,
        const float* __restrict__ ssinv,
        const float* __restrict__ AW,
        const float* __restrict__ W3, const float* __restrict__ bias,
        const float* __restrict__ Wt, float* __restrict__ t) {
    __shared__ float sAW[HDIM * HDIM * 2];
    for (int i = threadIdx.x; i < 2048; i += 512)
        ((float4*)sAW)[i] = ((const float4*)AW)[i];
    __syncthreads();
    int wid = blockIdx.x * 8 + (threadIdx.x >> 6);
    int lane = threadIdx.x & 63;
    if (wid >= N) return;
    int beg = __builtin_amdgcn_readfirstlane(rowptr[wid]);
    int end = __builtin_amdgcn_readfirstlane(rowptr[wid + 1]);
    int deg = end - beg;
    int w = lane & 31;
    int half = lane >> 5;
    float acc0 = 0.f, acc1 = 0.f;
    for (int tbase = beg; tbase < end; tbase += 64) {
        int cnt = min(64, end - tbase);
        int sv = (lane < cnt) ? (int)csr[tbase + lane] : -1;
        for (int u = 0; u < cnt; u += 8) {
            int i0 = __builtin_amdgcn_readlane(sv, u);
            int i1 = __builtin_amdgcn_readlane(sv, u + 1);
            int i2 = __builtin_amdgcn_readlane(sv, u + 2);
            int i3 = __builtin_amdgcn_readlane(sv, u + 3);
            int i4 = __builtin_amdgcn_readlane(sv, u + 4);
            int i5 = __builtin_amdgcn_readlane(sv, u + 5);
            int i6 = __builtin_amdgcn_readlane(sv, u + 6);
            int i7 = __builtin_amdgcn_readlane(sv, u + 7);
            int a0 = half ? i1 : i0;
            int a1 = half ? i3 : i2;
            int a2 = half ? i5 : i4;
            int a3 = half ? i7 : i6;
            if (a0 >= 0) { unsigned d = xinP[(size_t)a0 * 32 + w]; acc0 += bf_lo(d); acc1 += bf_hi(d); }
            if (a1 >= 0) { unsigned d = xinP[(size_t)a1 * 32 + w]; acc0 += bf_lo(d); acc1 += bf_hi(d); }
            if (a2 >= 0) { unsigned d = xinP[(size_t)a2 * 32 + w]; acc0 += bf_lo(d); acc1 += bf_hi(d); }
            if (a3 >= 0) { unsigned d = xinP[(size_t)a3 * 32 + w]; acc0 += bf_lo(d); acc1 += bf_hi(d); }
        }
    }
    acc0 += __shfl_xor(acc0, 32, 64);
    acc1 += __shfl_xor(acc1, 32, 64);
    float invd = 1.f / (float)max(deg, 1);
    float M0 = acc0 * invd;
    float M1 = acc1 * invd;
    unsigned xw = xinP[(size_t)wid * 32 + (lane >> 1)];
    float xi = (lane & 1) ? bf_hi(xw) : bf_lo(xw);
    float y = ssinv[wid] * W3[lane] + bias[lane];
#pragma unroll
    for (int k = 0; k < 64; ++k) {
        float xk = lane_bcast(xi, k);
        float Mk = lane_bcast((k & 1) ? M1 : M0, k >> 1);
        const float2 wv = *(const float2*)&sAW[(size_t)(k * 64 + lane) * 2];
        y += xk * wv.x + Mk * wv.y;
    }
    if (deg == 0) y = 0.f;
    if (RES) {
        unsigned rw = xresP[(size_t)wid * 32 + (lane >> 1)];
        y += (lane & 1) ? bf_hi(rw) : bf_lo(rw);
    }
    y = (y > 0.f) ? y : NEG_SLOPE * y;
    if (TOUT) {
        float tp = y * Wt[lane];
        for (int m = 32; m >= 1; m >>= 1) tp += __shfl_xor(tp, m, 64);
        if (lane == 0) t[wid] = tp;
    }
    float ylo = __shfl(y, (2 * lane) & 63, 64);
    float yhi = __shfl(y, (2 * lane + 1) & 63, 64);
    unsigned pkd = ((unsigned)f2bf(yhi) << 16) | (unsigned)f2bf(ylo);
    if (lane < 32) xoutP[(size_t)wid * 32 + lane] = pkd;
}

// conv_out + residual x
__global__ void k_out(int N, const unsigned* __restrict__ xAP, const float* __restrict__ x0,
                      const int* __restrict__ rowptr, const unsigned short* __restrict__ csr,
                      const float* __restrict__ ssinv, const float* __restrict__ t,
                      const float* __restrict__ W_out, const float* __restrict__ b_out,
                      float* __restrict__ out) {
    int wid = blockIdx.x * (blockDim.x >> 6) + (threadIdx.x >> 6);
    int lane = threadIdx.x & 63;
    if (wid >= N) return;
    int beg = rowptr[wid], end = rowptr[wid + 1];
    int deg = end - beg;
    float s = 0.f;
    for (int e = beg + lane; e < end; e += 64) s += t[csr[e]];
    unsigned xw = xAP[(size_t)wid * 32 + (lane >> 1)];
    float xf = (lane & 1) ? bf_hi(xw) : bf_lo(xw);
    float p = xf * (W_out[lane] - W_out[64 + lane]);
    for (int m = 32; m >= 1; m >>= 1) {
        s += __shfl_xor(s, m, 64);
        p += __shfl_xor(p, m, 64);
    }
    float invd = 1.f / (float)max(deg, 1);
    float y = p + s * invd + ssinv[wid] * W_out[128] + b_out[0];
    if (deg == 0) y = 0.f;
    if (lane == 0) out[wid] = y + x0[wid];
}

static inline size_t align16(size_t x) { return (x + 15) & ~(size_t)15; }

extern "C" void kernel_launch(void* const* d_in, const int* in_sizes, int n_in,
                              void* d_out, int out_size, void* d_ws, size_t ws_size,
                              hipStream_t stream) {
    const float* x0    = (const float*)d_in[0];
    const int*   ei    = (const int*)d_in[1];
    const float* W_in  = (const float*)d_in[2];
    const float* b_in  = (const float*)d_in[3];
    const float* W_mid = (const float*)d_in[4];
    const float* b_mid = (const float*)d_in[5];
    const float* W_out = (const float*)d_in[6];
    const float* b_out = (const float*)d_in[7];
    float* out = (float*)d_out;

    const int N = in_sizes[0];
    const int E = in_sizes[1] / 2;
    const int L = in_sizes[4] / (129 * 64);
    const int NB = (N + 127) >> 7;
    const int* src = ei;
    const int* dst = ei + E;

    char* p = (char*)d_ws;
    float* AW          = (float*)p; p += align16((size_t)L * HDIM * HDIM * 2 * 4);
    unsigned* xAP      = (unsigned*)p; p += align16((size_t)N * 32 * 4);
    unsigned* xBP      = (unsigned*)p; p += align16((size_t)N * 32 * 4);
    unsigned* bucketed = (unsigned*)p; p += align16((size_t)NB * CAPB * 4);
    unsigned short* csr = (unsigned short*)p; p += align16((size_t)E * 2);
    int* gcur          = (int*)p; p += align16((size_t)(NB + 1) * 4);
    int* gstart        = (int*)p; p += align16((size_t)(NB + 1) * 4);
    int* rowptr        = (int*)p; p += align16((size_t)(N + 1) * 4);
    float* ssinv       = (float*)p; p += align16((size_t)N * 4);
    float* t           = (float*)p; p += align16((size_t)N * 4);

    const int nb_w4 = (N + 3) / 4;
    const int nb_w8 = (N + 7) / 8;
    const int atotal = L * HDIM * HDIM;
    const int nb_bkt = (E + 8191) / 8192;

    k_initcur<<<(NB + 255) / 256, 256, 0, stream>>>(NB, gcur);
    k_bucket<<<nb_bkt, 256, 0, stream>>>(E, src, dst, gcur, bucketed, NB);
    k_bktscan<<<1, 512, 0, stream>>>(NB, N, gcur, gstart, rowptr);
    k_csr<<<NB, 256, 0, stream>>>(N, bucketed, gcur, gstart, csr, rowptr, ssinv);
    k_prep<<<(atotal + 255) / 256, 256, 0, stream>>>(atotal, W_mid, AW);

    k_in<<<nb_w4, 256, 0, stream>>>(N, x0, rowptr, csr, ssinv, W_in, b_in, xAP);

    for (int l = 0; l < L / 2; ++l) {
        const float* Wa = W_mid + (size_t)(2 * l) * 129 * 64;
        const float* Wb = W_mid + (size_t)(2 * l + 1) * 129 * 64;
        bool last = (l == L / 2 - 1);
        k_mid<false, false><<<nb_w8, 512, 0, stream>>>(
            N, xAP, nullptr, xBP, rowptr, csr, ssinv,
            AW + (size_t)(2 * l) * HDIM * HDIM * 2, Wa + 128 * 64,
            b_mid + (size_t)(2 * l) * HDIM, nullptr, nullptr);
        if (!last) {
            k_mid<true, false><<<nb_w8, 512, 0, stream>>>(
                N, xBP, xAP, xAP, rowptr, csr, ssinv,
                AW + (size_t)(2 * l + 1) * HDIM * HDIM * 2, Wb + 128 * 64,
                b_mid + (size_t)(2 * l + 1) * HDIM, nullptr, nullptr);
        } else {
            k_mid<true, true><<<nb_w8, 512, 0, stream>>>(
                N, xBP, xAP, xAP, rowptr, csr, ssinv,
                AW + (size_t)(2 * l + 1) * HDIM * HDIM * 2, Wb + 128 * 64,
                b_mid + (size_t)(2 * l + 1) * HDIM, W_out + 64, t);
        }
    }

    k_out<<<nb_w4, 256, 0, stream>>>(N, xAP, x0, rowptr, csr, ssinv, t,
                                     W_out, b_out, out);
}